// Round 5
// baseline (318.564 us; speedup 1.0000x reference)
//
#include <hip/hip_runtime.h>
#include <hip/hip_bf16.h>

// Problem constants
#define T_IN   16384
#define T_OUT  16376
#define CIN    64
#define NF     64
#define KT     9
#define NB     32
#define TILE   128                 // output rows per tile
#define ROWS   136                 // TILE + KT - 1 staged input rows
#define CGS    8                   // 8-channel chunk groups (16 B of bf16 each)
#define PLANE  (ROWS * 8)          // shorts per cg plane = 1088 (2176 B)
#define NBLOCKS 512
#define TILE_ITERS 8               // 512 blocks * 8 tiles = 4096 = 32 batches * 128 tiles
#define WS_SHORTS ((size_t)NB * T_IN * CIN)          // 33554432 shorts
#define WS_BYTES  (WS_SHORTS * 2)                    // 67108864 B

typedef __bf16 bf16x8 __attribute__((ext_vector_type(8)));
typedef unsigned short u16x8 __attribute__((ext_vector_type(8)));
typedef unsigned short u16x4 __attribute__((ext_vector_type(4)));
typedef float f32x16 __attribute__((ext_vector_type(16)));

// fp32 -> bf16 round-to-nearest-even (bit twiddle)
__device__ __forceinline__ unsigned short f2bf(float f) {
    unsigned u = __builtin_bit_cast(unsigned, f);
    u += 0x7FFFu + ((u >> 16) & 1u);
    return (unsigned short)(u >> 16);
}

// Async global->LDS DMA, 16B per lane; LDS dest = wave-uniform base + lane*16.
__device__ __forceinline__ void async_load16(const unsigned short* g, unsigned short* l) {
    __builtin_amdgcn_global_load_lds(
        (const __attribute__((address_space(1))) void*)g,
        (__attribute__((address_space(3))) void*)l, 16, 0, 0);
}

// ---------------- Pre-pass: x fp32 [32][16384][64] -> ws bf16 planes [32][8][16384][8] ----------------
__global__ __launch_bounds__(256) void convert_bf16_kernel(
    const float* __restrict__ x, unsigned short* __restrict__ ws)
{
    const int tid = blockIdx.x * 256 + threadIdx.x;   // 2048 blocks -> 524288 threads
#pragma unroll
    for (int i = 0; i < 8; ++i) {
        const int idx = tid + i * 524288;             // 0 .. 4194303 = 32*16384*8 items
        const int bb  = idx >> 17;                    // / (16384*8)
        const int rem = idx & 131071;
        const int t   = rem >> 3;
        const int cg  = rem & 7;
        const float* xp = x + ((size_t)bb * T_IN + t) * CIN + cg * 8;
        const float4 v0 = *(const float4*)xp;
        const float4 v1 = *(const float4*)(xp + 4);
        u16x8 p;
        p[0] = f2bf(v0.x); p[1] = f2bf(v0.y); p[2] = f2bf(v0.z); p[3] = f2bf(v0.w);
        p[4] = f2bf(v1.x); p[5] = f2bf(v1.y); p[6] = f2bf(v1.z); p[7] = f2bf(v1.w);
        *(u16x8*)&ws[((size_t)(bb * CGS + cg) * T_IN + t) * 8] = p;
    }
}

// ---------------- Main kernel: MFMA conv from pre-converted bf16 planes ----------------
__global__ __launch_bounds__(256, 2) void conv1d_mfma_dma_kernel(
    const unsigned short* __restrict__ xb,  // [32][8][16384][8] bf16
    const float* __restrict__ w,            // [64][9][64]
    const float* __restrict__ b,            // [64]
    float* __restrict__ out)                // [32][16376][64]
{
    // Double-buffered bf16 tile, plane-major: [buf][cg][row][8ch] (2 x 17408 B)
    __shared__ __attribute__((aligned(16))) unsigned short ldsX[2][CGS * PLANE];

    const int tid  = threadIdx.x;
    const int lane = tid & 63;
    const int wv   = tid >> 6;        // 4 waves
    const int half = lane >> 5;       // 0/1: k-half of MFMA operand
    const int l31  = lane & 31;
    const int fh   = wv & 1;          // filter half
    const int rh   = wv >> 1;         // row half
    const int rbase = rh * 64;
    const int fcol  = fh * 32 + l31;  // this lane's output filter column

    // ---- Weight B-fragments in registers (once per block) ----
    // B[k_inner][n]: n = lane&31 (filter), k_inner = half*8 + j -> channel = s*16 + half*8 + j
    bf16x8 Bf[KT][4];
#pragma unroll
    for (int k = 0; k < KT; ++k) {
#pragma unroll
        for (int s = 0; s < 4; ++s) {
            const float* wp = w + (size_t)fcol * (KT * CIN) + k * CIN + s * 16 + half * 8;
            const float4 w0 = *(const float4*)(wp);
            const float4 w1 = *(const float4*)(wp + 4);
            u16x8 t;
            t[0] = f2bf(w0.x); t[1] = f2bf(w0.y); t[2] = f2bf(w0.z); t[3] = f2bf(w0.w);
            t[4] = f2bf(w1.x); t[5] = f2bf(w1.y); t[6] = f2bf(w1.z); t[7] = f2bf(w1.w);
            Bf[k][s] = __builtin_bit_cast(bf16x8, t);
        }
    }
    const float bias = b[fcol];

    const int base = blockIdx.x * TILE_ITERS;

    // ---- Async DMA staging of tile g into buffer d (zero registers held) ----
    // 24 instrs: per cg plane, 64-row blocks at r0 = 0, 64, 72 (72..127 benignly rewritten)
    auto stage = [&](int g, int d) {
        const int bb = g >> 7;
        const int t0 = (g & 127) << 7;
        for (int j = wv; j < 24; j += 4) {
            const int cg = j / 3;
            const int p  = j - cg * 3;
            const int r0 = (p == 0) ? 0 : (p == 1) ? 64 : 72;
            int gr = t0 + r0 + lane;
            gr = gr < T_IN ? gr : (T_IN - 1);     // clamp (last tile only; discarded)
            const unsigned short* gp = xb + ((size_t)(bb * CGS + cg) * T_IN + gr) * 8;
            async_load16(gp, &ldsX[d][(cg * ROWS + r0) * 8]);
        }
    };

    // ---- Prologue ----
    stage(base, 0);
    __syncthreads();                 // compiler's vmcnt(0) drain = DMA arrival

    for (int it = 0; it < TILE_ITERS; ++it) {
        const int g  = base + it;
        const int bb = g >> 7;
        const int t0 = (g & 127) << 7;
        const int c  = it & 1;
        const bool more = (it + 1 < TILE_ITERS);

        // Issue next tile's DMA; flies under the MFMA phase, lands by the barrier.
        if (more) stage(g + 1, c ^ 1);

        // ---- MFMA main loop on buffer c ----
        // A-read: row = rbase + l31 + k, plane cg = s*2 + half -> one base + immediates,
        // lanes read consecutive 16B within a plane -> conflict-free.
        f32x16 acc0 = {0,0,0,0,0,0,0,0,0,0,0,0,0,0,0,0};
        f32x16 acc1 = {0,0,0,0,0,0,0,0,0,0,0,0,0,0,0,0};
        const unsigned short* lx = &ldsX[c][half * PLANE + (rbase + l31) * 8];
#pragma unroll
        for (int k = 0; k < KT; ++k) {
#pragma unroll
            for (int s = 0; s < 4; ++s) {
                const int off = s * (2 * PLANE) + k * 8;
                bf16x8 a0 = *(const bf16x8*)&lx[off];
                bf16x8 a1 = *(const bf16x8*)&lx[off + 256];   // +32 rows
                acc0 = __builtin_amdgcn_mfma_f32_32x32x16_bf16(a0, Bf[k][s], acc0, 0, 0, 0);
                acc1 = __builtin_amdgcn_mfma_f32_32x32x16_bf16(a1, Bf[k][s], acc1, 0, 0, 0);
            }
        }

        // ---- Epilogue BEFORE barrier: acc dies here (no spill across staging) ----
        // C/D layout col=lane&31, row=(reg&3)+8*(reg>>2)+4*(lane>>5)
#pragma unroll
        for (int m = 0; m < 2; ++m) {
            const f32x16 A = m ? acc1 : acc0;
#pragma unroll
            for (int r = 0; r < 16; ++r) {
                const int tl = rbase + m * 32 + (r & 3) + 8 * (r >> 2) + 4 * half;
                const int tg = t0 + tl;
                if (tg < T_OUT)
                    out[((size_t)bb * T_OUT + tg) * NF + fcol] = A[r] + bias;
            }
        }

        __syncthreads();   // single barrier: drains next-tile DMA (vmcnt) and orders
                           // this tile's LDS reads vs next staging overwrite
    }
}

// ---------------- Fallback (proven R0 kernel) if workspace is too small ----------------
#define LDS_STRIDE 72
__global__ __launch_bounds__(256, 2) void conv1d_fallback(
    const float* __restrict__ x, const float* __restrict__ w,
    const float* __restrict__ b, float* __restrict__ out)
{
    __shared__ __attribute__((aligned(16))) unsigned short ldsF[ROWS * LDS_STRIDE];
    const int tid  = threadIdx.x;
    const int lane = tid & 63;
    const int wv   = tid >> 6;
    const int half = lane >> 5;
    const int l31  = lane & 31;
    const int rbase = (wv >> 1) * 64;
    const int fcol  = (wv & 1) * 32 + l31;

    bf16x8 Bf[KT][4];
#pragma unroll
    for (int k = 0; k < KT; ++k) {
#pragma unroll
        for (int s = 0; s < 4; ++s) {
            const float* wp = w + (size_t)fcol * (KT * CIN) + k * CIN + s * 16 + half * 8;
            const float4 w0 = *(const float4*)(wp);
            const float4 w1 = *(const float4*)(wp + 4);
            u16x8 t;
            t[0] = f2bf(w0.x); t[1] = f2bf(w0.y); t[2] = f2bf(w0.z); t[3] = f2bf(w0.w);
            t[4] = f2bf(w1.x); t[5] = f2bf(w1.y); t[6] = f2bf(w1.z); t[7] = f2bf(w1.w);
            Bf[k][s] = __builtin_bit_cast(bf16x8, t);
        }
    }
    const float bias = b[fcol];

    for (int it = 0; it < TILE_ITERS; ++it) {
        const int g  = blockIdx.x * TILE_ITERS + it;
        const int bb = g >> 7;
        const int t0 = (g & 127) << 7;
        for (int i = tid; i < ROWS * 16; i += 256) {
            const int r  = i >> 4;
            const int cg = i & 15;
            int gr = t0 + r;
            gr = gr < (T_IN - 1) ? gr : (T_IN - 1);
            const float4 v = *(const float4*)(x + ((size_t)bb * T_IN + gr) * CIN + cg * 4);
            u16x4 p;
            p[0] = f2bf(v.x); p[1] = f2bf(v.y); p[2] = f2bf(v.z); p[3] = f2bf(v.w);
            *(u16x4*)&ldsF[r * LDS_STRIDE + cg * 4] = p;
        }
        __syncthreads();
        f32x16 acc0 = {0,0,0,0,0,0,0,0,0,0,0,0,0,0,0,0};
        f32x16 acc1 = {0,0,0,0,0,0,0,0,0,0,0,0,0,0,0,0};
        const int abase = (rbase + l31) * LDS_STRIDE + half * 8;
#pragma unroll
        for (int k = 0; k < KT; ++k) {
#pragma unroll
            for (int s = 0; s < 4; ++s) {
                const int off = abase + k * LDS_STRIDE + s * 16;
                bf16x8 a0 = *(const bf16x8*)&ldsF[off];
                bf16x8 a1 = *(const bf16x8*)&ldsF[off + 32 * LDS_STRIDE];
                acc0 = __builtin_amdgcn_mfma_f32_32x32x16_bf16(a0, Bf[k][s], acc0, 0, 0, 0);
                acc1 = __builtin_amdgcn_mfma_f32_32x32x16_bf16(a1, Bf[k][s], acc1, 0, 0, 0);
            }
        }
#pragma unroll
        for (int m = 0; m < 2; ++m) {
            const f32x16 A = m ? acc1 : acc0;
#pragma unroll
            for (int r = 0; r < 16; ++r) {
                const int tl = rbase + m * 32 + (r & 3) + 8 * (r >> 2) + 4 * half;
                const int tg = t0 + tl;
                if (tg < T_OUT)
                    out[((size_t)bb * T_OUT + tg) * NF + fcol] = A[r] + bias;
            }
        }
        __syncthreads();
    }
}

extern "C" void kernel_launch(void* const* d_in, const int* in_sizes, int n_in,
                              void* d_out, int out_size, void* d_ws, size_t ws_size,
                              hipStream_t stream) {
    const float* x = (const float*)d_in[0];
    const float* w = (const float*)d_in[1];
    const float* b = (const float*)d_in[2];
    float* out = (float*)d_out;
    if (ws_size >= WS_BYTES && d_ws != nullptr) {
        unsigned short* ws = (unsigned short*)d_ws;
        convert_bf16_kernel<<<2048, 256, 0, stream>>>(x, ws);
        conv1d_mfma_dma_kernel<<<NBLOCKS, 256, 0, stream>>>(ws, w, b, out);
    } else {
        conv1d_fallback<<<NBLOCKS, 256, 0, stream>>>(x, w, b, out);
    }
}